// Round 1
// baseline (201.440 us; speedup 1.0000x reference)
//
#include <hip/hip_runtime.h>
#include <math.h>

#define NBINS 31
#define NCOPIES 64
#define BLOCK 256
#define MAXGRID 2048

// Workspace layout (4-byte units): [0..30] float bin sums, [64..94] uint bin
// counts, [128] uint total_valid.

__device__ __forceinline__ void process_elem(float p, float t,
                                             float* my_sum, unsigned* my_cnt,
                                             unsigned& my_valid)
{
    bool valid = (t != -1.0f);
    my_valid += valid ? 1u : 0u;
    float nat = expm1f(t);
    if (valid && nat >= 0.0f) {
        int b = (int)fminf(floorf(nat), 30.0f);   // nat>=0 so floor>=0
        float base = fabsf(p - t);
        atomicAdd(&my_sum[b], base);              // ds_add_f32, lane-scrambled banks
        atomicAdd(&my_cnt[b], 1u);                // ds_add_u32
    }
}

__global__ __launch_bounds__(BLOCK) void zero_ws_kernel(unsigned* ws)
{
    int t = threadIdx.x;
    if (t < 192) ws[t] = 0u;
}

__global__ __launch_bounds__(BLOCK) void hist_kernel(
    const float* __restrict__ pred, const float* __restrict__ target, int n,
    float* __restrict__ g_sums, unsigned* __restrict__ g_cnts,
    unsigned* __restrict__ g_total)
{
    __shared__ float    s_sum[NCOPIES * NBINS];   // copy-major, stride 31 (bank-scrambled)
    __shared__ unsigned s_cnt[NCOPIES * NBINS];
    __shared__ float    p_sum[NBINS * 8];
    __shared__ unsigned p_cnt[NBINS * 8];
    __shared__ unsigned s_tot[BLOCK / 64];

    const int tid = threadIdx.x;
    for (int i = tid; i < NCOPIES * NBINS; i += BLOCK) { s_sum[i] = 0.0f; s_cnt[i] = 0u; }
    __syncthreads();

    const int lane = tid & 63;
    float*    my_sum = s_sum + lane * NBINS;
    unsigned* my_cnt = s_cnt + lane * NBINS;
    unsigned  my_valid = 0;

    const int n4 = n >> 2;
    const int gstride = gridDim.x * BLOCK;
    const float4* pred4 = (const float4*)pred;
    const float4* targ4 = (const float4*)target;

    for (int i = blockIdx.x * BLOCK + tid; i < n4; i += gstride) {
        float4 p = pred4[i];
        float4 t = targ4[i];
        process_elem(p.x, t.x, my_sum, my_cnt, my_valid);
        process_elem(p.y, t.y, my_sum, my_cnt, my_valid);
        process_elem(p.z, t.z, my_sum, my_cnt, my_valid);
        process_elem(p.w, t.w, my_sum, my_cnt, my_valid);
    }
    // scalar tail (n % 4 leftovers)
    for (int i = (n4 << 2) + blockIdx.x * BLOCK + tid; i < n; i += gstride) {
        process_elem(pred[i], target[i], my_sum, my_cnt, my_valid);
    }
    __syncthreads();

    // Stage 1: 64 copies -> 8 partials per bin (248 threads active)
    if (tid < NBINS * 8) {
        int b = tid >> 3, g = tid & 7;
        float fs = 0.0f; unsigned cs = 0u;
        #pragma unroll
        for (int k = 0; k < 8; ++k) {
            int c = g * 8 + k;
            fs += s_sum[c * NBINS + b];
            cs += s_cnt[c * NBINS + b];
        }
        p_sum[b * 8 + g] = fs;
        p_cnt[b * 8 + g] = cs;
    }
    // block-reduce valid count (wave shuffle, width 64)
    unsigned v = my_valid;
    #pragma unroll
    for (int off = 32; off >= 1; off >>= 1) v += __shfl_down(v, off, 64);
    if (lane == 0) s_tot[tid >> 6] = v;
    __syncthreads();

    // Stage 2: 8 partials -> 1 per bin, then one global atomic per bin
    if (tid < NBINS) {
        float fs = 0.0f; unsigned cs = 0u;
        #pragma unroll
        for (int g = 0; g < 8; ++g) { fs += p_sum[tid * 8 + g]; cs += p_cnt[tid * 8 + g]; }
        atomicAdd(&g_sums[tid], fs);
        atomicAdd(&g_cnts[tid], cs);
    }
    if (tid == 0) {
        unsigned tot = 0;
        #pragma unroll
        for (int w = 0; w < BLOCK / 64; ++w) tot += s_tot[w];
        atomicAdd(g_total, tot);
    }
}

__global__ void finalize_kernel(const float* __restrict__ g_sums,
                                const unsigned* __restrict__ g_cnts,
                                const unsigned* __restrict__ g_total,
                                float* __restrict__ out)
{
    int lane = threadIdx.x;  // 64 threads, one wave
    float denom = fmaxf((float)(*g_total), 1.0f);
    float contrib = 0.0f;
    if (lane < NBINS) {
        float freq = (float)g_cnts[lane] / denom;
        float w = 1.0f / (sqrtf(freq) + 1e-6f);   // ALPHA=0.5 -> sqrt
        contrib = g_sums[lane] * w;
    }
    #pragma unroll
    for (int off = 32; off >= 1; off >>= 1) contrib += __shfl_down(contrib, off, 64);
    if (lane == 0) *out = contrib / denom;
}

extern "C" void kernel_launch(void* const* d_in, const int* in_sizes, int n_in,
                              void* d_out, int out_size, void* d_ws, size_t ws_size,
                              hipStream_t stream)
{
    const float* pred   = (const float*)d_in[0];
    const float* target = (const float*)d_in[1];
    float* out = (float*)d_out;
    int n = in_sizes[0];

    float*    g_sums  = (float*)d_ws;
    unsigned* g_cnts  = (unsigned*)d_ws + 64;
    unsigned* g_total = (unsigned*)d_ws + 128;

    zero_ws_kernel<<<1, BLOCK, 0, stream>>>((unsigned*)d_ws);

    int n4 = n >> 2;
    int blocks = (n4 + BLOCK - 1) / BLOCK;
    if (blocks > MAXGRID) blocks = MAXGRID;
    if (blocks < 1) blocks = 1;
    hist_kernel<<<blocks, BLOCK, 0, stream>>>(pred, target, n, g_sums, g_cnts, g_total);

    finalize_kernel<<<1, 64, 0, stream>>>(g_sums, g_cnts, g_total, out);
}